// Round 1
// baseline (886.764 us; speedup 1.0000x reference)
//
#include <hip/hip_runtime.h>
#include <hip/hip_bf16.h>
#include <math.h>

// Problem constants (from reference)
#define B_ROWS 4096
#define C_ROWS 2048
#define D_DIM  2048
#define NUM 2
#define MAX_ITER 15
#define NEAREST 3
#define MARGIN 1.0f

// ---------------------------------------------------------------------------
// Row sum-of-squares: out[row] = sum_k X[row][k]^2
// ---------------------------------------------------------------------------
__global__ __launch_bounds__(256) void row_sumsq(const float* __restrict__ X,
                                                 float* __restrict__ out, int K) {
    int row = blockIdx.x;
    const float* p = X + (size_t)row * K;
    float s = 0.0f;
    for (int k = threadIdx.x; k < K; k += 256) {
        float v = p[k];
        s += v * v;
    }
    __shared__ float red[256];
    red[threadIdx.x] = s;
    __syncthreads();
    for (int off = 128; off >= 1; off >>= 1) {
        if ((int)threadIdx.x < off) red[threadIdx.x] += red[threadIdx.x + off];
        __syncthreads();
    }
    if (threadIdx.x == 0) out[row] = red[0];
}

// ---------------------------------------------------------------------------
// Tiled f32 GEMM producing squared distances:
//   Out[m][n] = a2[m] + b2[n] - 2 * sum_k A[m][k]*Bm[n][k]
// 64x64 tile, 256 threads, each thread computes a 4x4 micro-tile.
// ---------------------------------------------------------------------------
#define TS 64
#define KT 16
__global__ __launch_bounds__(256) void gemm_d2(const float* __restrict__ A,
                                               const float* __restrict__ Bm,
                                               const float* __restrict__ a2,
                                               const float* __restrict__ b2,
                                               float* __restrict__ Out,
                                               int M, int N, int K) {
    // pad +4 floats: keeps 16B alignment of 4-float groups, breaks 64-stride conflicts
    __shared__ float As[KT][TS + 4];
    __shared__ float Bs[KT][TS + 4];

    int tid = threadIdx.x;        // 0..255
    int tx = tid & 15;            // n-direction (0..15)
    int ty = tid >> 4;            // m-direction (0..15)
    int bm = blockIdx.y * TS;
    int bn = blockIdx.x * TS;

    float acc[4][4] = {};

    for (int k0 = 0; k0 < K; k0 += KT) {
        // Load 64(m) x 16(k) tiles of A and Bm; 1024 elems each, 4 per thread.
        #pragma unroll
        for (int i = 0; i < 4; ++i) {
            int idx = tid + i * 256;      // 0..1023
            int m  = idx >> 4;            // 0..63
            int kk = idx & 15;            // 0..15
            As[kk][m] = A[(size_t)(bm + m) * K + (k0 + kk)];
            Bs[kk][m] = Bm[(size_t)(bn + m) * K + (k0 + kk)];
        }
        __syncthreads();
        #pragma unroll
        for (int kk = 0; kk < KT; ++kk) {
            float av[4], bv[4];
            #pragma unroll
            for (int i = 0; i < 4; ++i) av[i] = As[kk][ty * 4 + i];
            #pragma unroll
            for (int j = 0; j < 4; ++j) bv[j] = Bs[kk][tx * 4 + j];
            #pragma unroll
            for (int i = 0; i < 4; ++i)
                #pragma unroll
                for (int j = 0; j < 4; ++j)
                    acc[i][j] += av[i] * bv[j];
        }
        __syncthreads();
    }

    #pragma unroll
    for (int i = 0; i < 4; ++i) {
        int m = bm + ty * 4 + i;
        float am = a2[m];
        #pragma unroll
        for (int j = 0; j < 4; ++j) {
            int n = bn + tx * 4 + j;
            Out[(size_t)m * N + n] = am + b2[n] - 2.0f * acc[i][j];
        }
    }
}

// ---------------------------------------------------------------------------
// For each center row of Dcc (squared distances), find indices of the 3
// smallest values (self included: d2[c][c] ~ 0 is always the min).
// One wave (64 threads) per row; each lane owns 32 strided elements.
// ---------------------------------------------------------------------------
__global__ __launch_bounds__(64) void near3_kernel(const float* __restrict__ Dcc,
                                                   int* __restrict__ near3, int C) {
    int c = blockIdx.x;
    int lane = threadIdx.x;          // 0..63
    const float* row = Dcc + (size_t)c * C;
    const int nj = C / 64;           // 32

    float vals[32];
    #pragma unroll
    for (int j = 0; j < 32; ++j) vals[j] = row[lane + j * 64];

    unsigned int excl = 0;
    for (int pick = 0; pick < NEAREST; ++pick) {
        float bestv = INFINITY;
        int bestidx = 0x7fffffff;
        #pragma unroll
        for (int j = 0; j < 32; ++j) {
            if (excl & (1u << j)) continue;
            float v = vals[j];
            int idx = lane + j * 64;
            if (v < bestv || (v == bestv && idx < bestidx)) { bestv = v; bestidx = idx; }
        }
        for (int off = 32; off >= 1; off >>= 1) {
            float ov = __shfl_down(bestv, off);
            int   oi = __shfl_down(bestidx, off);
            if (ov < bestv || (ov == bestv && oi < bestidx)) { bestv = ov; bestidx = oi; }
        }
        int sel = __shfl(bestidx, 0);
        if (lane == 0) near3[c * NEAREST + pick] = sel;
        if ((sel & 63) == lane) excl |= 1u << (sel >> 6);
    }
    (void)nj;
}

// ---------------------------------------------------------------------------
// Per feature row b: same = dist(b, label); iterate <=15 times over nearest
// "other" centers, stop at first trusted (label not in near3[sel]).
// hinge = max(MARGIN + same - min_diff, 0); atomic-accumulate mean.
// One wave per row.
// ---------------------------------------------------------------------------
__global__ __launch_bounds__(64) void select_kernel(const float* __restrict__ Dfc,
                                                    const int* __restrict__ near3,
                                                    float* __restrict__ out, int C) {
    int b = blockIdx.x;
    int lane = threadIdx.x;
    int label = b / NUM;
    const float* row = Dfc + (size_t)b * C;

    float vals[32];
    #pragma unroll
    for (int j = 0; j < 32; ++j) {
        int cc = lane + j * 64;
        float v = row[cc];
        vals[j] = (cc == label) ? INFINITY : v;
    }

    unsigned int excl = 0;
    float min_diff = 0.0f;
    int found = 0;
    for (int it = 0; it < MAX_ITER; ++it) {
        float bestv = INFINITY;
        int bestidx = 0x7fffffff;
        #pragma unroll
        for (int j = 0; j < 32; ++j) {
            if (excl & (1u << j)) continue;
            float v = vals[j];
            int idx = lane + j * 64;
            if (v < bestv || (v == bestv && idx < bestidx)) { bestv = v; bestidx = idx; }
        }
        for (int off = 32; off >= 1; off >>= 1) {
            float ov = __shfl_down(bestv, off);
            int   oi = __shfl_down(bestidx, off);
            if (ov < bestv || (ov == bestv && oi < bestidx)) { bestv = ov; bestidx = oi; }
        }
        int sel = __shfl(bestidx, 0);
        float selv = __shfl(bestv, 0);
        // trust check: label must not be among the 3 nearest centers of sel
        bool trusted = (near3[sel * NEAREST + 0] != label) &&
                       (near3[sel * NEAREST + 1] != label) &&
                       (near3[sel * NEAREST + 2] != label);
        if (trusted) {
            min_diff = sqrtf(fmaxf(selv, 0.0f));
            found = 1;
            break;
        }
        if ((sel & 63) == lane) excl |= 1u << (sel >> 6);
    }

    if (lane == 0) {
        float same = sqrtf(fmaxf(row[label], 0.0f));
        float md = found ? min_diff : 0.0f;
        float hinge = fmaxf(MARGIN + same - md, 0.0f);
        atomicAdd(out, hinge * (1.0f / (float)B_ROWS));
    }
}

// ---------------------------------------------------------------------------
extern "C" void kernel_launch(void* const* d_in, const int* in_sizes, int n_in,
                              void* d_out, int out_size, void* d_ws, size_t ws_size,
                              hipStream_t stream) {
    const float* feature = (const float*)d_in[0];  // 4096 x 2048
    const float* centers = (const float*)d_in[1];  // 2048 x 2048
    float* out = (float*)d_out;                    // scalar

    // Workspace layout (floats)
    float* Dfc   = (float*)d_ws;                          // 4096*2048
    float* Dcc   = Dfc + (size_t)B_ROWS * C_ROWS;         // 2048*2048
    float* f2    = Dcc + (size_t)C_ROWS * C_ROWS;         // 4096
    float* c2    = f2 + B_ROWS;                           // 2048
    int*   near3 = (int*)(c2 + C_ROWS);                   // 2048*3

    hipMemsetAsync(d_out, 0, out_size * sizeof(float), stream);

    row_sumsq<<<B_ROWS, 256, 0, stream>>>(feature, f2, D_DIM);
    row_sumsq<<<C_ROWS, 256, 0, stream>>>(centers, c2, D_DIM);

    // D_cc squared distances (2048 x 2048)
    gemm_d2<<<dim3(C_ROWS / TS, C_ROWS / TS), 256, 0, stream>>>(
        centers, centers, c2, c2, Dcc, C_ROWS, C_ROWS, D_DIM);

    near3_kernel<<<C_ROWS, 64, 0, stream>>>(Dcc, near3, C_ROWS);

    // D_fc squared distances (4096 x 2048)
    gemm_d2<<<dim3(C_ROWS / TS, B_ROWS / TS), 256, 0, stream>>>(
        feature, centers, f2, c2, Dfc, B_ROWS, C_ROWS, D_DIM);

    select_kernel<<<B_ROWS, 64, 0, stream>>>(Dfc, near3, out, C_ROWS);
}

// Round 2
// 261.299 us; speedup vs baseline: 3.3937x; 3.3937x over previous
//
#include <hip/hip_runtime.h>
#include <hip/hip_bf16.h>
#include <math.h>

// Problem constants (from reference)
#define B_ROWS 4096
#define C_ROWS 2048
#define D_DIM  2048
#define NUM 2
#define MAX_ITER 15
#define NEAREST 3
#define MARGIN 1.0f

typedef __bf16 bf16_t;
typedef bf16_t bf16x4 __attribute__((ext_vector_type(4)));
typedef bf16_t bf16x8 __attribute__((ext_vector_type(8)));
typedef float f32x4 __attribute__((ext_vector_type(4)));

// ---------------------------------------------------------------------------
// Convert one row f32 -> bf16 and compute row sum-of-squares (f32 inputs).
// One block (256 threads) per row, K = 2048.
// ---------------------------------------------------------------------------
__global__ __launch_bounds__(256) void conv_row(const float* __restrict__ X,
                                                bf16_t* __restrict__ Xb,
                                                float* __restrict__ sq, int K) {
    int row = blockIdx.x;
    const float* p = X + (size_t)row * K;
    bf16_t* q = Xb + (size_t)row * K;
    float s = 0.0f;
    for (int k = threadIdx.x * 4; k < K; k += 256 * 4) {
        float4 v = *(const float4*)(p + k);
        s += v.x * v.x + v.y * v.y + v.z * v.z + v.w * v.w;
        bf16x4 b;
        b.x = (bf16_t)v.x; b.y = (bf16_t)v.y; b.z = (bf16_t)v.z; b.w = (bf16_t)v.w;
        *(bf16x4*)(q + k) = b;
    }
    __shared__ float red[256];
    red[threadIdx.x] = s;
    __syncthreads();
    for (int off = 128; off >= 1; off >>= 1) {
        if ((int)threadIdx.x < off) red[threadIdx.x] += red[threadIdx.x + off];
        __syncthreads();
    }
    if (threadIdx.x == 0) sq[row] = red[0];
}

// ---------------------------------------------------------------------------
// bf16 MFMA distance GEMM (m97 structure):
//   Out[m][n] = a2[m] + b2[n] - 2 * sum_k A[m][k]*B[n][k]
// 128x128 block tile, 256 threads = 4 waves in 2x2, each wave 64x64
// (4x4 grid of 16x16x32 MFMAs). BK=32. global_load_lds width-16 staging.
// M,N,K must be multiples of 128/128/32 (they are: 4096/2048/2048).
// ---------------------------------------------------------------------------
__global__ __launch_bounds__(256) void gemm_d2_mfma(const bf16_t* __restrict__ A,
                                                    const bf16_t* __restrict__ Bm,
                                                    const float* __restrict__ a2,
                                                    const float* __restrict__ b2,
                                                    float* __restrict__ Out,
                                                    int M, int N, int K) {
    // Row-major [128][32] bf16, NO padding (global_load_lds needs contiguous
    // lane order: wave-uniform base + lane*16B).
    __shared__ __align__(16) bf16_t As[128 * 32];
    __shared__ __align__(16) bf16_t Bs[128 * 32];

    const int tid  = threadIdx.x;
    const int wave = tid >> 6;
    const int lane = tid & 63;
    const int bm = blockIdx.y * 128;
    const int bn = blockIdx.x * 128;
    const int wm = (wave >> 1) * 64;   // wave row offset in tile
    const int wn = (wave & 1) * 64;    // wave col offset in tile

    f32x4 acc[4][4] = {};

    // Staging geometry: 8 chunks of 16 rows; wave w stages chunks 2w, 2w+1
    // for both A and B. Lane l covers row chunk*16 + (l>>2), bytes (l&3)*16.
    const int c0 = wave * 2;
    const int rsub = lane >> 2;          // 0..15
    const int ksub = (lane & 3) * 8;     // bf16 elems: 0,8,16,24 (16B each)

    const int mrow = lane & 15;
    const int kq   = (lane >> 4) * 8;

    for (int k0 = 0; k0 < K; k0 += 32) {
        // ---- stage A,B tiles into LDS (async, wave-uniform LDS base) ----
        #pragma unroll
        for (int is = 0; is < 2; ++is) {
            int chunk = c0 + is;
            int row = chunk * 16 + rsub;
            const bf16_t* gA = A + (size_t)(bm + row) * K + (k0 + ksub);
            const bf16_t* gB = Bm + (size_t)(bn + row) * K + (k0 + ksub);
            __builtin_amdgcn_global_load_lds(
                (const __attribute__((address_space(1))) void*)gA,
                (__attribute__((address_space(3))) void*)&As[chunk * 512], 16, 0, 0);
            __builtin_amdgcn_global_load_lds(
                (const __attribute__((address_space(1))) void*)gB,
                (__attribute__((address_space(3))) void*)&Bs[chunk * 512], 16, 0, 0);
        }
        __syncthreads();

        // ---- fragments + MFMA ----
        bf16x8 af[4], bf[4];
        #pragma unroll
        for (int i = 0; i < 4; ++i) {
            af[i] = *(const bf16x8*)&As[(wm + i * 16 + mrow) * 32 + kq];
            bf[i] = *(const bf16x8*)&Bs[(wn + i * 16 + mrow) * 32 + kq];
        }
        #pragma unroll
        for (int i = 0; i < 4; ++i)
            #pragma unroll
            for (int j = 0; j < 4; ++j)
                acc[i][j] = __builtin_amdgcn_mfma_f32_16x16x32_bf16(af[i], bf[j], acc[i][j], 0, 0, 0);
        __syncthreads();
    }

    // ---- epilogue: d2 = a2 + b2 - 2*dot ----
    // C/D layout (m89-verified): col = lane&15, row = (lane>>4)*4 + reg
    const int ncol = lane & 15;
    const int r4   = (lane >> 4) * 4;
    #pragma unroll
    for (int i = 0; i < 4; ++i) {
        #pragma unroll
        for (int r = 0; r < 4; ++r) {
            int m = bm + wm + i * 16 + r4 + r;
            float am = a2[m];
            #pragma unroll
            for (int j = 0; j < 4; ++j) {
                int n = bn + wn + j * 16 + ncol;
                Out[(size_t)m * N + n] = am + b2[n] - 2.0f * acc[i][j][r];
            }
        }
    }
}

// ---------------------------------------------------------------------------
// For each center row of Dcc (squared distances), indices of 3 smallest.
// One wave per row.
// ---------------------------------------------------------------------------
__global__ __launch_bounds__(64) void near3_kernel(const float* __restrict__ Dcc,
                                                   int* __restrict__ near3, int C) {
    int c = blockIdx.x;
    int lane = threadIdx.x;
    const float* row = Dcc + (size_t)c * C;

    float vals[32];
    #pragma unroll
    for (int j = 0; j < 32; ++j) vals[j] = row[lane + j * 64];

    unsigned int excl = 0;
    for (int pick = 0; pick < NEAREST; ++pick) {
        float bestv = INFINITY;
        int bestidx = 0x7fffffff;
        #pragma unroll
        for (int j = 0; j < 32; ++j) {
            if (excl & (1u << j)) continue;
            float v = vals[j];
            int idx = lane + j * 64;
            if (v < bestv || (v == bestv && idx < bestidx)) { bestv = v; bestidx = idx; }
        }
        for (int off = 32; off >= 1; off >>= 1) {
            float ov = __shfl_down(bestv, off);
            int   oi = __shfl_down(bestidx, off);
            if (ov < bestv || (ov == bestv && oi < bestidx)) { bestv = ov; bestidx = oi; }
        }
        int sel = __shfl(bestidx, 0);
        if (lane == 0) near3[c * NEAREST + pick] = sel;
        if ((sel & 63) == lane) excl |= 1u << (sel >> 6);
    }
}

// ---------------------------------------------------------------------------
// Per feature row: iterative argmin-with-exclusion, first trusted center.
// ---------------------------------------------------------------------------
__global__ __launch_bounds__(64) void select_kernel(const float* __restrict__ Dfc,
                                                    const int* __restrict__ near3,
                                                    float* __restrict__ out, int C) {
    int b = blockIdx.x;
    int lane = threadIdx.x;
    int label = b / NUM;
    const float* row = Dfc + (size_t)b * C;

    float vals[32];
    #pragma unroll
    for (int j = 0; j < 32; ++j) {
        int cc = lane + j * 64;
        float v = row[cc];
        vals[j] = (cc == label) ? INFINITY : v;
    }

    unsigned int excl = 0;
    float min_diff = 0.0f;
    int found = 0;
    for (int it = 0; it < MAX_ITER; ++it) {
        float bestv = INFINITY;
        int bestidx = 0x7fffffff;
        #pragma unroll
        for (int j = 0; j < 32; ++j) {
            if (excl & (1u << j)) continue;
            float v = vals[j];
            int idx = lane + j * 64;
            if (v < bestv || (v == bestv && idx < bestidx)) { bestv = v; bestidx = idx; }
        }
        for (int off = 32; off >= 1; off >>= 1) {
            float ov = __shfl_down(bestv, off);
            int   oi = __shfl_down(bestidx, off);
            if (ov < bestv || (ov == bestv && oi < bestidx)) { bestv = ov; bestidx = oi; }
        }
        int sel = __shfl(bestidx, 0);
        float selv = __shfl(bestv, 0);
        bool trusted = (near3[sel * NEAREST + 0] != label) &&
                       (near3[sel * NEAREST + 1] != label) &&
                       (near3[sel * NEAREST + 2] != label);
        if (trusted) {
            min_diff = sqrtf(fmaxf(selv, 0.0f));
            found = 1;
            break;
        }
        if ((sel & 63) == lane) excl |= 1u << (sel >> 6);
    }

    if (lane == 0) {
        float same = sqrtf(fmaxf(row[label], 0.0f));
        float md = found ? min_diff : 0.0f;
        float hinge = fmaxf(MARGIN + same - md, 0.0f);
        atomicAdd(out, hinge * (1.0f / (float)B_ROWS));
    }
}

// ---------------------------------------------------------------------------
extern "C" void kernel_launch(void* const* d_in, const int* in_sizes, int n_in,
                              void* d_out, int out_size, void* d_ws, size_t ws_size,
                              hipStream_t stream) {
    const float* feature = (const float*)d_in[0];  // 4096 x 2048
    const float* centers = (const float*)d_in[1];  // 2048 x 2048
    float* out = (float*)d_out;                    // scalar

    // Workspace layout
    float*  Dfc  = (float*)d_ws;                           // 4096*2048 f32
    float*  Dcc  = Dfc + (size_t)B_ROWS * C_ROWS;          // 2048*2048 f32
    bf16_t* Fbf  = (bf16_t*)(Dcc + (size_t)C_ROWS * C_ROWS); // 4096*2048 bf16
    bf16_t* Cbf  = Fbf + (size_t)B_ROWS * D_DIM;           // 2048*2048 bf16
    float*  f2   = (float*)(Cbf + (size_t)C_ROWS * D_DIM); // 4096
    float*  c2   = f2 + B_ROWS;                            // 2048
    int*    near3 = (int*)(c2 + C_ROWS);                   // 2048*3

    hipMemsetAsync(d_out, 0, out_size * sizeof(float), stream);

    conv_row<<<B_ROWS, 256, 0, stream>>>(feature, Fbf, f2, D_DIM);
    conv_row<<<C_ROWS, 256, 0, stream>>>(centers, Cbf, c2, D_DIM);

    // D_cc squared distances (2048 x 2048)
    gemm_d2_mfma<<<dim3(C_ROWS / 128, C_ROWS / 128), 256, 0, stream>>>(
        Cbf, Cbf, c2, c2, Dcc, C_ROWS, C_ROWS, D_DIM);

    near3_kernel<<<C_ROWS, 64, 0, stream>>>(Dcc, near3, C_ROWS);

    // D_fc squared distances (4096 x 2048)
    gemm_d2_mfma<<<dim3(C_ROWS / 128, B_ROWS / 128), 256, 0, stream>>>(
        Fbf, Cbf, f2, c2, Dfc, B_ROWS, C_ROWS, D_DIM);

    select_kernel<<<B_ROWS, 64, 0, stream>>>(Dfc, near3, out, C_ROWS);
}

// Round 3
// 201.133 us; speedup vs baseline: 4.4088x; 1.2991x over previous
//
#include <hip/hip_runtime.h>
#include <hip/hip_bf16.h>
#include <math.h>

// Problem constants (from reference)
#define B_ROWS 4096
#define C_ROWS 2048
#define D_DIM  2048
#define NUM 2
#define MAX_ITER 15
#define NEAREST 3
#define MARGIN 1.0f

typedef __bf16 bf16_t;
typedef bf16_t bf16x4 __attribute__((ext_vector_type(4)));
typedef bf16_t bf16x8 __attribute__((ext_vector_type(8)));
typedef float f32x4 __attribute__((ext_vector_type(4)));

// ---------------------------------------------------------------------------
// Fused conversion: rows [0,4096) = feature, rows [4096,6144) = centers.
// f32 -> bf16 plus row sum-of-squares. One 256-thread block per row.
// ---------------------------------------------------------------------------
__global__ __launch_bounds__(256) void conv_rows(const float* __restrict__ F,
                                                 const float* __restrict__ Cn,
                                                 bf16_t* __restrict__ Fb,
                                                 bf16_t* __restrict__ Cb,
                                                 float* __restrict__ f2,
                                                 float* __restrict__ c2) {
    int row = blockIdx.x;
    const float* p;
    bf16_t* q;
    float* sq;
    int r;
    if (row < B_ROWS) {
        r = row;
        p = F + (size_t)r * D_DIM;
        q = Fb + (size_t)r * D_DIM;
        sq = f2;
    } else {
        r = row - B_ROWS;
        p = Cn + (size_t)r * D_DIM;
        q = Cb + (size_t)r * D_DIM;
        sq = c2;
    }
    float s = 0.0f;
    for (int k = threadIdx.x * 4; k < D_DIM; k += 256 * 4) {
        float4 v = *(const float4*)(p + k);
        s += v.x * v.x + v.y * v.y + v.z * v.z + v.w * v.w;
        bf16x4 b;
        b.x = (bf16_t)v.x; b.y = (bf16_t)v.y; b.z = (bf16_t)v.z; b.w = (bf16_t)v.w;
        *(bf16x4*)(q + k) = b;
    }
    __shared__ float red[256];
    red[threadIdx.x] = s;
    __syncthreads();
    for (int off = 128; off >= 1; off >>= 1) {
        if ((int)threadIdx.x < off) red[threadIdx.x] += red[threadIdx.x + off];
        __syncthreads();
    }
    if (threadIdx.x == 0) sq[r] = red[0];
}

// ---------------------------------------------------------------------------
// Fused bf16 MFMA distance GEMM (both Dfc and Dcc in one dispatch):
//   Out[m][n] = a2[m] + c2[n] - 2 * sum_k A[m][k]*Cb[n][k]
// blockIdx.y < 32 -> Dfc rows (A=Fb), else -> Dcc rows (A=Cb).
// 128x128 tile, 4 waves (2x2 of 64x64), 16x16x32 MFMA, BK=32,
// width-16 global_load_lds staging. Grid (16,48) = 768 blocks = 3/CU.
// ---------------------------------------------------------------------------
__global__ __launch_bounds__(256) void gemm_d2_fused(const bf16_t* __restrict__ Fb,
                                                     const bf16_t* __restrict__ Cb,
                                                     const float* __restrict__ f2,
                                                     const float* __restrict__ c2,
                                                     float* __restrict__ Dfc,
                                                     float* __restrict__ Dcc) {
    __shared__ __align__(16) bf16_t As[128 * 32];
    __shared__ __align__(16) bf16_t Bs[128 * 32];

    const int tid  = threadIdx.x;
    const int wave = tid >> 6;
    const int lane = tid & 63;

    const int by = blockIdx.y;
    const bf16_t* A;
    const float* a2v;
    float* Out;
    int bm;
    if (by < B_ROWS / 128) {
        A = Fb; a2v = f2; Out = Dfc; bm = by * 128;
    } else {
        A = Cb; a2v = c2; Out = Dcc; bm = (by - B_ROWS / 128) * 128;
    }
    const int bn = blockIdx.x * 128;
    const int N = C_ROWS;
    const int K = D_DIM;

    const int wm = (wave >> 1) * 64;
    const int wn = (wave & 1) * 64;

    f32x4 acc[4][4] = {};

    // Staging: 8 chunks of 16 rows; wave w stages chunks 2w, 2w+1 (A and B).
    const int c0 = wave * 2;
    const int rsub = lane >> 2;          // 0..15
    const int ksub = (lane & 3) * 8;     // 0,8,16,24 (16B)

    const int mrow = lane & 15;
    const int kq   = (lane >> 4) * 8;

    for (int k0 = 0; k0 < K; k0 += 32) {
        #pragma unroll
        for (int is = 0; is < 2; ++is) {
            int chunk = c0 + is;
            int row = chunk * 16 + rsub;
            const bf16_t* gA = A + (size_t)(bm + row) * K + (k0 + ksub);
            const bf16_t* gB = Cb + (size_t)(bn + row) * K + (k0 + ksub);
            __builtin_amdgcn_global_load_lds(
                (const __attribute__((address_space(1))) void*)gA,
                (__attribute__((address_space(3))) void*)&As[chunk * 512], 16, 0, 0);
            __builtin_amdgcn_global_load_lds(
                (const __attribute__((address_space(1))) void*)gB,
                (__attribute__((address_space(3))) void*)&Bs[chunk * 512], 16, 0, 0);
        }
        __syncthreads();

        bf16x8 af[4], bf[4];
        #pragma unroll
        for (int i = 0; i < 4; ++i) {
            af[i] = *(const bf16x8*)&As[(wm + i * 16 + mrow) * 32 + kq];
            bf[i] = *(const bf16x8*)&Bs[(wn + i * 16 + mrow) * 32 + kq];
        }
        #pragma unroll
        for (int i = 0; i < 4; ++i)
            #pragma unroll
            for (int j = 0; j < 4; ++j)
                acc[i][j] = __builtin_amdgcn_mfma_f32_16x16x32_bf16(af[i], bf[j], acc[i][j], 0, 0, 0);
        __syncthreads();
    }

    // Epilogue: d2 = a2[m] + c2[n] - 2*dot. C/D: col=lane&15, row=(lane>>4)*4+reg
    const int ncol = lane & 15;
    const int r4   = (lane >> 4) * 4;
    #pragma unroll
    for (int i = 0; i < 4; ++i) {
        #pragma unroll
        for (int r = 0; r < 4; ++r) {
            int m = bm + wm + i * 16 + r4 + r;
            float am = a2v[m];
            #pragma unroll
            for (int j = 0; j < 4; ++j) {
                int n = bn + wn + j * 16 + ncol;
                Out[(size_t)m * N + n] = am + c2[n] - 2.0f * acc[i][j][r];
            }
        }
    }
}

// ---------------------------------------------------------------------------
// near3: indices of 3 smallest per Dcc row. 4 waves/block, one row per wave.
// ---------------------------------------------------------------------------
__global__ __launch_bounds__(256) void near3_kernel(const float* __restrict__ Dcc,
                                                    int* __restrict__ near3, int C) {
    int wave = threadIdx.x >> 6;
    int lane = threadIdx.x & 63;
    int c = blockIdx.x * 4 + wave;
    const float* row = Dcc + (size_t)c * C;

    float vals[32];
    #pragma unroll
    for (int j = 0; j < 32; ++j) vals[j] = row[lane + j * 64];

    unsigned int excl = 0;
    for (int pick = 0; pick < NEAREST; ++pick) {
        float bestv = INFINITY;
        int bestidx = 0x7fffffff;
        #pragma unroll
        for (int j = 0; j < 32; ++j) {
            if (excl & (1u << j)) continue;
            float v = vals[j];
            int idx = lane + j * 64;
            if (v < bestv || (v == bestv && idx < bestidx)) { bestv = v; bestidx = idx; }
        }
        for (int off = 32; off >= 1; off >>= 1) {
            float ov = __shfl_down(bestv, off);
            int   oi = __shfl_down(bestidx, off);
            if (ov < bestv || (ov == bestv && oi < bestidx)) { bestv = ov; bestidx = oi; }
        }
        int sel = __shfl(bestidx, 0);
        if (lane == 0) near3[c * NEAREST + pick] = sel;
        if ((sel & 63) == lane) excl |= 1u << (sel >> 6);
    }
}

// ---------------------------------------------------------------------------
// select: per feature row, iterative argmin-with-exclusion, first trusted.
// 4 waves/block, one row per wave, LDS-reduce -> 1 atomic per block.
// ---------------------------------------------------------------------------
__global__ __launch_bounds__(256) void select_kernel(const float* __restrict__ Dfc,
                                                     const int* __restrict__ near3,
                                                     float* __restrict__ out, int C) {
    int wave = threadIdx.x >> 6;
    int lane = threadIdx.x & 63;
    int b = blockIdx.x * 4 + wave;
    int label = b / NUM;
    const float* row = Dfc + (size_t)b * C;

    float vals[32];
    #pragma unroll
    for (int j = 0; j < 32; ++j) {
        int cc = lane + j * 64;
        float v = row[cc];
        vals[j] = (cc == label) ? INFINITY : v;
    }

    unsigned int excl = 0;
    float min_diff = 0.0f;
    int found = 0;
    for (int it = 0; it < MAX_ITER; ++it) {
        float bestv = INFINITY;
        int bestidx = 0x7fffffff;
        #pragma unroll
        for (int j = 0; j < 32; ++j) {
            if (excl & (1u << j)) continue;
            float v = vals[j];
            int idx = lane + j * 64;
            if (v < bestv || (v == bestv && idx < bestidx)) { bestv = v; bestidx = idx; }
        }
        for (int off = 32; off >= 1; off >>= 1) {
            float ov = __shfl_down(bestv, off);
            int   oi = __shfl_down(bestidx, off);
            if (ov < bestv || (ov == bestv && oi < bestidx)) { bestv = ov; bestidx = oi; }
        }
        int sel = __shfl(bestidx, 0);
        float selv = __shfl(bestv, 0);
        bool trusted = (near3[sel * NEAREST + 0] != label) &&
                       (near3[sel * NEAREST + 1] != label) &&
                       (near3[sel * NEAREST + 2] != label);
        if (trusted) {
            min_diff = sqrtf(fmaxf(selv, 0.0f));
            found = 1;
            break;
        }
        if ((sel & 63) == lane) excl |= 1u << (sel >> 6);
    }

    __shared__ float hs[4];
    if (lane == 0) {
        float same = sqrtf(fmaxf(row[label], 0.0f));
        float md = found ? min_diff : 0.0f;
        hs[wave] = fmaxf(MARGIN + same - md, 0.0f);
    }
    __syncthreads();
    if (threadIdx.x == 0) {
        float h = hs[0] + hs[1] + hs[2] + hs[3];
        atomicAdd(out, h * (1.0f / (float)B_ROWS));
    }
}

// ---------------------------------------------------------------------------
extern "C" void kernel_launch(void* const* d_in, const int* in_sizes, int n_in,
                              void* d_out, int out_size, void* d_ws, size_t ws_size,
                              hipStream_t stream) {
    const float* feature = (const float*)d_in[0];  // 4096 x 2048
    const float* centers = (const float*)d_in[1];  // 2048 x 2048
    float* out = (float*)d_out;                    // scalar

    // Workspace layout
    float*  Dfc  = (float*)d_ws;                             // 4096*2048 f32
    float*  Dcc  = Dfc + (size_t)B_ROWS * C_ROWS;            // 2048*2048 f32
    bf16_t* Fbf  = (bf16_t*)(Dcc + (size_t)C_ROWS * C_ROWS); // 4096*2048 bf16
    bf16_t* Cbf  = Fbf + (size_t)B_ROWS * D_DIM;             // 2048*2048 bf16
    float*  f2   = (float*)(Cbf + (size_t)C_ROWS * D_DIM);   // 4096
    float*  c2   = f2 + B_ROWS;                              // 2048
    int*    near3 = (int*)(c2 + C_ROWS);                     // 2048*3

    hipMemsetAsync(d_out, 0, out_size * sizeof(float), stream);

    conv_rows<<<B_ROWS + C_ROWS, 256, 0, stream>>>(feature, centers, Fbf, Cbf, f2, c2);

    // Both distance matrices in one dispatch: grid (16, 32+16) = 768 blocks.
    gemm_d2_fused<<<dim3(C_ROWS / 128, B_ROWS / 128 + C_ROWS / 128), 256, 0, stream>>>(
        Fbf, Cbf, f2, c2, Dfc, Dcc);

    near3_kernel<<<C_ROWS / 4, 256, 0, stream>>>(Dcc, near3, C_ROWS);

    select_kernel<<<B_ROWS / 4, 256, 0, stream>>>(Dfc, near3, out, C_ROWS);
}